// Round 14
// baseline (276.241 us; speedup 1.0000x reference)
//
#include <hip/hip_runtime.h>

// BinaryLinear: out = (x @ sign(w)^T) * alpha[o],  alpha = mean(|w|, axis=1)
// x: [65536,1024] f32, w: [1024,1024] f32, out: [65536,1024] f32
//
// R14: spill-proof rebuild of the fp16-prepass design. R13's post-timing
//      divergence is attributed to counted-vmcnt gates miscounting when the
//      allocator spills (scratch traffic is VMEM -> gate retires spills, not
//      staging DMAs -> tile read before DMA lands, intermittently).
//      Fix: __syncthreads() only (compiler-paired full drain), low live-reg
//      COMPUTE. BK=64, double-buffered fp16 A+B (128KB LDS), 16 phases.
//      x16 (128MB) fits L3 -> GEMM A-reads are L3-hits. 8-slot XOR swizzle.

typedef _Float16 half8 __attribute__((ext_vector_type(8)));
typedef _Float16 half4v __attribute__((ext_vector_type(4)));
typedef float f32x4 __attribute__((ext_vector_type(4)));

#define TOKENS 65536
#define INF 1024
#define OUTF 1024
#define BM 256
#define BN 256

__device__ __forceinline__ void gload_lds16(const void* g, void* l) {
  __builtin_amdgcn_global_load_lds(
      (const __attribute__((address_space(1))) unsigned int*)g,
      (__attribute__((address_space(3))) unsigned int*)l, 16, 0, 0);
}

__device__ __forceinline__ half8 cvt8(f32x4 a, f32x4 b) {
  half8 h;
  h[0] = (_Float16)a[0]; h[1] = (_Float16)a[1];
  h[2] = (_Float16)a[2]; h[3] = (_Float16)a[3];
  h[4] = (_Float16)b[0]; h[5] = (_Float16)b[1];
  h[6] = (_Float16)b[2]; h[7] = (_Float16)b[3];
  return h;
}

// ---------------- prep: alpha + sign(fp16) ----------------
__global__ __launch_bounds__(256) void bl_prep(const float* __restrict__ w,
                                               _Float16* __restrict__ sbin,
                                               float* __restrict__ alpha) {
  const int o = blockIdx.x;
  const int tid = threadIdx.x;
  const float4 v = ((const float4*)(w + (size_t)o * INF))[tid];
  float s = fabsf(v.x) + fabsf(v.y) + fabsf(v.z) + fabsf(v.w);
  half4v h;
  h[0] = (_Float16)((v.x > 0.f) ? 1.f : ((v.x < 0.f) ? -1.f : 0.f));
  h[1] = (_Float16)((v.y > 0.f) ? 1.f : ((v.y < 0.f) ? -1.f : 0.f));
  h[2] = (_Float16)((v.z > 0.f) ? 1.f : ((v.z < 0.f) ? -1.f : 0.f));
  h[3] = (_Float16)((v.w > 0.f) ? 1.f : ((v.w < 0.f) ? -1.f : 0.f));
  *(half4v*)(sbin + (size_t)o * INF + tid * 4) = h;
#pragma unroll
  for (int off = 32; off > 0; off >>= 1) s += __shfl_down(s, off, 64);
  __shared__ float red[4];
  const int wave = tid >> 6, lane = tid & 63;
  if (lane == 0) red[wave] = s;
  __syncthreads();
  if (tid == 0) alpha[o] = (red[0] + red[1] + red[2] + red[3]) * (1.0f / 1024.0f);
}

// ---------------- prepass: x f32 -> fp16 ----------------
__global__ __launch_bounds__(256) void bl_cvt(const float* __restrict__ x,
                                              _Float16* __restrict__ x16) {
  const size_t stride = (size_t)gridDim.x * 256 * 8;
  for (size_t i = ((size_t)blockIdx.x * 256 + threadIdx.x) * 8;
       i < (size_t)TOKENS * INF; i += stride) {
    f32x4 v0 = *(const f32x4*)(x + i);
    f32x4 v1 = *(const f32x4*)(x + i + 4);
    *(half8*)(x16 + i) = cvt8(v0, v1);
  }
}

// ---------------- GEMM, all-fp16, BK=64, dbuf, syncthreads ----------------
__global__ __launch_bounds__(512) void bl_gemm16(const _Float16* __restrict__ x16,
                                                 const _Float16* __restrict__ sbin,
                                                 const float* __restrict__ alpha,
                                                 float* __restrict__ out) {
  __shared__ _Float16 ldsA[2][BM * 64]; // 2 x 32KB
  __shared__ _Float16 ldsB[2][BN * 64]; // 2 x 32KB  (128KB)

  const int tid = threadIdx.x;
  const int lane = tid & 63;
  const int wid = tid >> 6;
  const int l15 = lane & 15;
  const int kc = lane >> 4; // 0..3
  const int wr = wid >> 1;  // 0..3 (64-row slice)
  const int wc = wid & 1;   // 0..1 (128-col slice)

  const int bid = blockIdx.x;
  const int wgid = (bid & 7) * 128 + (bid >> 3);
  const int bm0 = (wgid >> 2) * BM;
  const int bn0 = (wgid & 3) * BN;

  // staging: 32KB tile = 2048 x 16B chunks; thread owns 4.
  // LDS[row][slot s] holds source chunk s ^ (row&7)  (8-slot involution)
  int aSrc[4], bSrc[4]; // element offsets (fit in int)
  int dst[4];
#pragma unroll
  for (int q = 0; q < 4; ++q) {
    const int ci = q * 512 + tid;
    const int row = ci >> 3;
    const int c = (ci & 7) ^ (row & 7);
    aSrc[q] = (bm0 + row) * INF + c * 8;
    bSrc[q] = (bn0 + row) * INF + c * 8;
    dst[q] = ci * 16; // linear LDS byte dest (wave-uniform base + lane*16)
  }
  // fragment reads: row stride 128B; slot(ks) = (ks*4+kc) ^ (l15&7)
  int slotKs[2];
#pragma unroll
  for (int ks = 0; ks < 2; ++ks) slotKs[ks] = (((ks * 4 + kc) ^ (l15 & 7)) << 4);
  int aRd[4];
#pragma unroll
  for (int mf = 0; mf < 4; ++mf) aRd[mf] = (wr * 64 + mf * 16 + l15) * 128;
  int bRd[8];
#pragma unroll
  for (int nf = 0; nf < 8; ++nf) bRd[nf] = (wc * 128 + nf * 16 + l15) * 128;

  f32x4 acc[4][8] = {};

#define STAGE(SB_, tk_)                                                        \
  {                                                                            \
    const int ko_ = (tk_)*64;                                                  \
    gload_lds16(x16 + aSrc[0] + ko_, (char*)&ldsA[SB_][0] + dst[0]);           \
    gload_lds16(x16 + aSrc[1] + ko_, (char*)&ldsA[SB_][0] + dst[1]);           \
    gload_lds16(x16 + aSrc[2] + ko_, (char*)&ldsA[SB_][0] + dst[2]);           \
    gload_lds16(x16 + aSrc[3] + ko_, (char*)&ldsA[SB_][0] + dst[3]);           \
    gload_lds16(sbin + bSrc[0] + ko_, (char*)&ldsB[SB_][0] + dst[0]);          \
    gload_lds16(sbin + bSrc[1] + ko_, (char*)&ldsB[SB_][0] + dst[1]);          \
    gload_lds16(sbin + bSrc[2] + ko_, (char*)&ldsB[SB_][0] + dst[2]);          \
    gload_lds16(sbin + bSrc[3] + ko_, (char*)&ldsB[SB_][0] + dst[3]);          \
  }

#define MF4(AC_, B_)                                                           \
  acc[0][AC_] = __builtin_amdgcn_mfma_f32_16x16x32_f16(af0, B_, acc[0][AC_], 0, 0, 0); \
  acc[1][AC_] = __builtin_amdgcn_mfma_f32_16x16x32_f16(af1, B_, acc[1][AC_], 0, 0, 0); \
  acc[2][AC_] = __builtin_amdgcn_mfma_f32_16x16x32_f16(af2, B_, acc[2][AC_], 0, 0, 0); \
  acc[3][AC_] = __builtin_amdgcn_mfma_f32_16x16x32_f16(af3, B_, acc[3][AC_], 0, 0, 0);

// one K-slice (K=32) of one buffer; low live-reg form (b in 2 groups of 4)
#define KSLICE(RB_, KS_)                                                       \
  {                                                                            \
    const char* pa_ = (const char*)&ldsA[RB_][0];                              \
    const char* pb_ = (const char*)&ldsB[RB_][0];                              \
    const int sl_ = slotKs[KS_];                                               \
    const half8 af0 = *(const half8*)(pa_ + aRd[0] + sl_);                     \
    const half8 af1 = *(const half8*)(pa_ + aRd[1] + sl_);                     \
    const half8 af2 = *(const half8*)(pa_ + aRd[2] + sl_);                     \
    const half8 af3 = *(const half8*)(pa_ + aRd[3] + sl_);                     \
    half8 b0 = *(const half8*)(pb_ + bRd[0] + sl_);                            \
    half8 b1 = *(const half8*)(pb_ + bRd[1] + sl_);                            \
    half8 b2 = *(const half8*)(pb_ + bRd[2] + sl_);                            \
    half8 b3 = *(const half8*)(pb_ + bRd[3] + sl_);                            \
    MF4(0, b0) MF4(1, b1) MF4(2, b2) MF4(3, b3)                                \
    b0 = *(const half8*)(pb_ + bRd[4] + sl_);                                  \
    b1 = *(const half8*)(pb_ + bRd[5] + sl_);                                  \
    b2 = *(const half8*)(pb_ + bRd[6] + sl_);                                  \
    b3 = *(const half8*)(pb_ + bRd[7] + sl_);                                  \
    MF4(4, b0) MF4(5, b1) MF4(6, b2) MF4(7, b3)                                \
  }

#define COMPUTE(RB_)                                                           \
  {                                                                            \
    __builtin_amdgcn_s_setprio(1);                                             \
    KSLICE(RB_, 0)                                                             \
    KSLICE(RB_, 1)                                                             \
    __builtin_amdgcn_s_setprio(0);                                             \
  }

  // prologue
  STAGE(0, 0);
  __syncthreads(); // full drain (compiler-paired vmcnt(0)+lgkmcnt(0))

#pragma unroll 1
  for (int u = 0; u < 8; ++u) {
    STAGE(1, 2 * u + 1); // DMA overlaps the compute below; drained at barrier
    COMPUTE(0);
    __syncthreads();
    if (u < 7) STAGE(0, 2 * u + 2);
    COMPUTE(1);
    __syncthreads();
  }
#undef COMPUTE
#undef KSLICE
#undef MF4
#undef STAGE

  // epilogue: scale by alpha[col], store f32
  float al[8];
#pragma unroll
  for (int n = 0; n < 8; ++n) al[n] = alpha[bn0 + wc * 128 + n * 16 + l15];
#pragma unroll
  for (int mf = 0; mf < 4; ++mf) {
    const int row0 = bm0 + wr * 64 + mf * 16 + kc * 4;
#pragma unroll
    for (int n = 0; n < 8; ++n) {
      const int col = bn0 + wc * 128 + n * 16 + l15;
#pragma unroll
      for (int j = 0; j < 4; ++j)
        out[(size_t)(row0 + j) * OUTF + col] = acc[mf][n][j] * al[n];
    }
  }
}

// ---------------- fallback: f32-A, BK=32, dbuf, syncthreads ----------------
__global__ __launch_bounds__(512) void bl_gemm32(const float* __restrict__ x,
                                                 const _Float16* __restrict__ sbin,
                                                 const float* __restrict__ alpha,
                                                 float* __restrict__ out) {
  __shared__ float ldsA[2][BM * 32];    // 2 x 32KB
  __shared__ _Float16 ldsB[2][BN * 32]; // 2 x 16KB (96KB)

  const int tid = threadIdx.x;
  const int lane = tid & 63;
  const int wid = tid >> 6;
  const int l15 = lane & 15;
  const int kc = lane >> 4;
  const int wr = wid >> 1;
  const int wc = wid & 1;

  const int bid = blockIdx.x;
  const int wgid = (bid & 7) * 128 + (bid >> 3);
  const int bm0 = (wgid >> 2) * BM;
  const int bn0 = (wgid & 3) * BN;

  int aSrc[4], aDst[4];
#pragma unroll
  for (int q = 0; q < 4; ++q) {
    const int ci = q * 512 + tid;
    const int row = ci >> 3;
    const int c = (ci & 7) ^ (row & 7);
    aSrc[q] = (bm0 + row) * INF + c * 4;
    aDst[q] = ci * 16;
  }
  int bSrc[2], bDst[2];
#pragma unroll
  for (int p = 0; p < 2; ++p) {
    const int ci = p * 512 + tid;
    const int row = ci >> 2;
    const int c = (ci & 3) ^ ((row >> 1) & 3);
    bSrc[p] = (bn0 + row) * INF + c * 8;
    bDst[p] = ci * 16;
  }
  int aRd[4][2];
#pragma unroll
  for (int mf = 0; mf < 4; ++mf) {
    const int row = wr * 64 + mf * 16 + l15;
#pragma unroll
    for (int d = 0; d < 2; ++d)
      aRd[mf][d] = row * 128 + (((2 * kc + d) ^ (row & 7)) << 4);
  }
  int bRd[8];
#pragma unroll
  for (int nf = 0; nf < 8; ++nf) {
    const int row = wc * 128 + nf * 16 + l15;
    bRd[nf] = row * 64 + ((kc ^ ((row >> 1) & 3)) << 4);
  }

  f32x4 acc[4][8] = {};

#define STAGE(SB_, tk_)                                                        \
  {                                                                            \
    const int ko_ = (tk_)*32;                                                  \
    gload_lds16(x + aSrc[0] + ko_, (char*)&ldsA[SB_][0] + aDst[0]);            \
    gload_lds16(x + aSrc[1] + ko_, (char*)&ldsA[SB_][0] + aDst[1]);            \
    gload_lds16(x + aSrc[2] + ko_, (char*)&ldsA[SB_][0] + aDst[2]);            \
    gload_lds16(x + aSrc[3] + ko_, (char*)&ldsA[SB_][0] + aDst[3]);            \
    gload_lds16(sbin + bSrc[0] + ko_, (char*)&ldsB[SB_][0] + bDst[0]);         \
    gload_lds16(sbin + bSrc[1] + ko_, (char*)&ldsB[SB_][0] + bDst[1]);         \
  }

#define MF4(AC_, B_)                                                           \
  acc[0][AC_] = __builtin_amdgcn_mfma_f32_16x16x32_f16(af0, B_, acc[0][AC_], 0, 0, 0); \
  acc[1][AC_] = __builtin_amdgcn_mfma_f32_16x16x32_f16(af1, B_, acc[1][AC_], 0, 0, 0); \
  acc[2][AC_] = __builtin_amdgcn_mfma_f32_16x16x32_f16(af2, B_, acc[2][AC_], 0, 0, 0); \
  acc[3][AC_] = __builtin_amdgcn_mfma_f32_16x16x32_f16(af3, B_, acc[3][AC_], 0, 0, 0);

#define COMPUTE(RB_)                                                           \
  {                                                                            \
    const char* pa_ = (const char*)&ldsA[RB_][0];                              \
    const char* pb_ = (const char*)&ldsB[RB_][0];                              \
    f32x4 lo0 = *(const f32x4*)(pa_ + aRd[0][0]);                              \
    f32x4 hi0 = *(const f32x4*)(pa_ + aRd[0][1]);                              \
    f32x4 lo1 = *(const f32x4*)(pa_ + aRd[1][0]);                              \
    f32x4 hi1 = *(const f32x4*)(pa_ + aRd[1][1]);                              \
    const half8 af0 = cvt8(lo0, hi0);                                          \
    const half8 af1 = cvt8(lo1, hi1);                                          \
    lo0 = *(const f32x4*)(pa_ + aRd[2][0]);                                    \
    hi0 = *(const f32x4*)(pa_ + aRd[2][1]);                                    \
    lo1 = *(const f32x4*)(pa_ + aRd[3][0]);                                    \
    hi1 = *(const f32x4*)(pa_ + aRd[3][1]);                                    \
    const half8 af2 = cvt8(lo0, hi0);                                          \
    const half8 af3 = cvt8(lo1, hi1);                                          \
    __builtin_amdgcn_s_setprio(1);                                             \
    half8 b0 = *(const half8*)(pb_ + bRd[0]);                                  \
    half8 b1 = *(const half8*)(pb_ + bRd[1]);                                  \
    half8 b2 = *(const half8*)(pb_ + bRd[2]);                                  \
    half8 b3 = *(const half8*)(pb_ + bRd[3]);                                  \
    MF4(0, b0) MF4(1, b1) MF4(2, b2) MF4(3, b3)                                \
    b0 = *(const half8*)(pb_ + bRd[4]);                                        \
    b1 = *(const half8*)(pb_ + bRd[5]);                                        \
    b2 = *(const half8*)(pb_ + bRd[6]);                                        \
    b3 = *(const half8*)(pb_ + bRd[7]);                                        \
    MF4(4, b0) MF4(5, b1) MF4(6, b2) MF4(7, b3)                                \
    __builtin_amdgcn_s_setprio(0);                                             \
  }

  STAGE(0, 0);
  __syncthreads();

#pragma unroll 1
  for (int u = 0; u < 16; ++u) {
    STAGE(1, 2 * u + 1);
    COMPUTE(0);
    __syncthreads();
    if (u < 15) STAGE(0, 2 * u + 2);
    COMPUTE(1);
    __syncthreads();
  }
#undef COMPUTE
#undef MF4
#undef STAGE

  float al[8];
#pragma unroll
  for (int n = 0; n < 8; ++n) al[n] = alpha[bn0 + wc * 128 + n * 16 + l15];
#pragma unroll
  for (int mf = 0; mf < 4; ++mf) {
    const int row0 = bm0 + wr * 64 + mf * 16 + kc * 4;
#pragma unroll
    for (int n = 0; n < 8; ++n) {
      const int col = bn0 + wc * 128 + n * 16 + l15;
#pragma unroll
      for (int j = 0; j < 4; ++j)
        out[(size_t)(row0 + j) * OUTF + col] = acc[mf][n][j] * al[n];
    }
  }
}

extern "C" void kernel_launch(void* const* d_in, const int* in_sizes, int n_in,
                              void* d_out, int out_size, void* d_ws, size_t ws_size,
                              hipStream_t stream) {
  const float* x = (const float*)d_in[0];
  const float* w = (const float*)d_in[1];
  float* out = (float*)d_out;

  const size_t x16_bytes = (size_t)TOKENS * INF * 2; // 128 MiB
  const size_t sbin_bytes = (size_t)OUTF * INF * 2;  // 2 MiB
  const size_t needed = x16_bytes + sbin_bytes + OUTF * 4;

  if (ws_size >= needed) {
    _Float16* x16 = (_Float16*)d_ws;
    _Float16* sbin = (_Float16*)((char*)d_ws + x16_bytes);
    float* alpha = (float*)((char*)d_ws + x16_bytes + sbin_bytes);
    bl_prep<<<dim3(OUTF), dim3(256), 0, stream>>>(w, sbin, alpha);
    bl_cvt<<<dim3(2048), dim3(256), 0, stream>>>(x, x16);
    bl_gemm16<<<dim3((TOKENS / BM) * (OUTF / BN)), dim3(512), 0, stream>>>(x16, sbin, alpha, out);
  } else {
    _Float16* sbin = (_Float16*)d_ws;
    float* alpha = (float*)((char*)d_ws + sbin_bytes);
    bl_prep<<<dim3(OUTF), dim3(256), 0, stream>>>(w, sbin, alpha);
    bl_gemm32<<<dim3((TOKENS / BM) * (OUTF / BN)), dim3(512), 0, stream>>>(x, sbin, alpha, out);
  }
}